// Round 1
// baseline (374.155 us; speedup 1.0000x reference)
//
#include <hip/hip_runtime.h>
#include <hip/hip_bf16.h>

#define NN 3072
#define CCC 16
#define HH 128
#define KTOP 4
#define NCLS 455   // C(15,3)
#define NUP 120    // 15 singles + 105 pairs
#define EPSF 1e-5f

// ---------------- ws layout (float offsets) ----------------
#define OFF_F       0
#define SZ_F        (16*NCLS*HH)            // 931840
#define OFF_CNT     (OFF_F + SZ_F)          // class counts (float), 7280
#define SZ_CNT      (16*NCLS)
#define OFF_SUMS    (OFF_CNT + SZ_CNT)      // sumHc[16], sumSq[16]
#define SZ_SUMS     32
#define OFF_NCNT    (OFF_SUMS + SZ_SUMS)    // int nodeCnt[16]
#define SZ_NCNT     16
#define ZERO_FLOATS (OFF_NCNT + SZ_NCNT)
#define OFF_LOGITS  ZERO_FLOATS
#define SZ_LOGITS   (NN*CCC)
#define OFF_COLS    (OFF_LOGITS + SZ_LOGITS)   // int, per (n,slot)
#define SZ_E        (NN*KTOP)
#define OFF_RANKS   (OFF_COLS + SZ_E)          // int
#define OFF_FISEL   (OFF_RANKS + SZ_E)         // float
#define OFF_NLIST   (OFF_FISEL + SZ_E)         // int, 16*NN
#define SZ_NLIST    (16*NN)
#define OFF_UP      (OFF_NLIST + SZ_NLIST)     // 16*120*128
#define SZ_UP       (16*NUP*HH)
#define OFF_AGG     (OFF_UP + SZ_UP)           // 16*455*128
#define OFF_INVDEG  (OFF_AGG + SZ_F)           // 7280
#define OFF_HC      (OFF_INVDEG + SZ_CNT)      // 12288*128
#define SZ_HC       (NN*KTOP*HH)

__device__ __forceinline__ int C2i(int x){ return x*(x-1)/2; }
__device__ __forceinline__ int C3i(int x){ return x*(x-1)*(x-2)/6; }

// rank -> triple bitmask over 15 relabeled columns
__device__ __forceinline__ unsigned decode_mask(int r){
  int c = 2; while (c < 14 && C3i(c+1) <= r) c++;
  int rem = r - C3i(c);
  int b = 1; while (b < c-1 && C2i(b+1) <= rem) b++;
  int a = rem - C2i(b);
  return (1u<<a) | (1u<<b) | (1u<<c);
}

// ---------------- stage A: z=relu(X@W1^T+b1); LN; logit=zn.W2+b2 ----------------
#define ROWS 16
__global__ __launch_bounds__(128) void k_logits(const float* __restrict__ X,
    const float* __restrict__ W1, const float* __restrict__ b1,
    const float* __restrict__ ln_g, const float* __restrict__ ln_b,
    const float* __restrict__ W2, const float* __restrict__ b2,
    float* __restrict__ logits){
  __shared__ float xs[ROWS][HH];
  __shared__ float mu_s[ROWS], rs_s[ROWS];
  int t = threadIdx.x;
  int base = blockIdx.x * ROWS;            // flat row = n*C + c
  for (int i = 0; i < ROWS; ++i) xs[i][t] = X[(base+i)*HH + t];
  __syncthreads();
  float acc[ROWS];
  #pragma unroll
  for (int i=0;i<ROWS;++i) acc[i]=0.f;
  const float* w1r = W1 + t*HH;
  for (int h=0; h<HH; h+=4){
    float4 w4 = *(const float4*)(w1r + h);
    #pragma unroll
    for (int i=0;i<ROWS;++i)
      acc[i] += xs[i][h]*w4.x + xs[i][h+1]*w4.y + xs[i][h+2]*w4.z + xs[i][h+3]*w4.w;
  }
  float bb = b1[t];
  __syncthreads();
  #pragma unroll
  for (int i=0;i<ROWS;++i){ float z = acc[i]+bb; xs[i][t] = z>0.f?z:0.f; }
  __syncthreads();
  if (t < ROWS){
    float s1=0.f, s2=0.f;
    for (int h=0;h<HH;++h){ float v=xs[t][h]; s1+=v; s2+=v*v; }
    float mu = s1/(float)HH;
    float var = s2/(float)HH - mu*mu;
    mu_s[t]=mu; rs_s[t]=1.0f/sqrtf(var+EPSF);
  }
  __syncthreads();
  float gg = ln_g[t], lb = ln_b[t], w2 = W2[t];
  #pragma unroll
  for (int i=0;i<ROWS;++i){
    float zn = (xs[i][t]-mu_s[i])*rs_s[i]*gg + lb;
    xs[i][t] = zn*w2;
  }
  __syncthreads();
  if (t < ROWS){
    float s=0.f; for (int h=0;h<HH;++h) s += xs[t][h];
    logits[base+t] = s + b2[0];
  }
}

// ---------------- stage B: softmax fi, top-4, class ranks, node lists ----------------
__global__ __launch_bounds__(256) void k_topk(const float* __restrict__ logits,
    int* __restrict__ cols, int* __restrict__ ranks, float* __restrict__ fiSel,
    int* __restrict__ nodeCnt, int* __restrict__ nodeList){
  int n = blockIdx.x*256 + threadIdx.x;
  if (n >= NN) return;
  float l[CCC];
  #pragma unroll
  for (int c=0;c<CCC;++c) l[c] = logits[n*CCC+c];
  // top-4 on logits (softmax is monotone); tie -> lowest index (jax.lax.top_k)
  unsigned mask = 0;
  #pragma unroll
  for (int k=0;k<KTOP;++k){
    float best = -3e38f; int bi = 0;
    #pragma unroll
    for (int c=0;c<CCC;++c){
      bool taken = (mask>>c)&1u;
      if (!taken && l[c] > best){ best = l[c]; bi = c; }
    }
    mask |= 1u<<bi;
  }
  float m = -3e38f;
  #pragma unroll
  for (int c=0;c<CCC;++c) m = l[c]>m ? l[c] : m;
  float s = 0.f;
  #pragma unroll
  for (int c=0;c<CCC;++c) s += expf(l[c]-m);
  float inv = 1.0f/s;
  // iterate selected columns in ascending order
  unsigned m2 = mask;
  for (int j=0;j<KTOP;++j){
    int ci = __ffs(m2)-1; m2 &= m2-1u;
    unsigned rest = mask & ~(1u<<ci);
    int v[3]; unsigned r2 = rest;
    #pragma unroll
    for (int q=0;q<3;++q){ int col = __ffs(r2)-1; r2 &= r2-1u; v[q] = col - (col>ci ? 1:0); }
    int rank = C3i(v[2]) + C2i(v[1]) + v[0];
    int e4 = n*KTOP + j;
    cols[e4] = ci; ranks[e4] = rank;
    fiSel[e4] = expf(logits[n*CCC+ci]-m)*inv;
    int pos = atomicAdd(&nodeCnt[ci], 1);
    nodeList[ci*NN + pos] = e4;
  }
}

// ---------------- stage C: class feature sums ----------------
__global__ __launch_bounds__(128) void k_accF(const float* __restrict__ X,
    const int* __restrict__ cols, const int* __restrict__ ranks,
    const float* __restrict__ fiSel, float* __restrict__ F, float* __restrict__ cnt){
  int e = blockIdx.x, h = threadIdx.x;
  int ci = cols[e], rank = ranks[e];
  float fi = fiSel[e];
  int n = e >> 2;
  float v = X[(n*CCC+ci)*HH + h] * fi;
  atomicAdd(&F[(ci*NCLS+rank)*HH + h], v);
  if (h==0) atomicAdd(&cnt[ci*NCLS+rank], 1.0f);
}

// ---------------- stage D1: singles U (15) and pairs P (105) per ci ----------------
__global__ __launch_bounds__(128) void k_up(const float* __restrict__ F, float* __restrict__ UP){
  __shared__ unsigned tm[NCLS];
  int t = threadIdx.x;
  for (int i=t;i<NCLS;i+=128) tm[i] = decode_mask(i);
  __syncthreads();
  int s = blockIdx.x, ci = blockIdx.y;
  unsigned need;
  if (s < 15) need = 1u<<s;
  else {
    int p = s-15;
    int pb = 1; while (pb < 14 && C2i(pb+1) <= p) pb++;
    int pa = p - C2i(pb);
    need = (1u<<pa)|(1u<<pb);
  }
  float acc = 0.f;
  const float* Fc = F + ci*NCLS*HH;
  for (int tp=0; tp<NCLS; ++tp)
    if ((tm[tp] & need) == need) acc += Fc[tp*HH + t];
  UP[(ci*NUP+s)*HH + t] = acc;
}

// ---------------- stage D2: degrees ----------------
__global__ __launch_bounds__(256) void k_deg(const float* __restrict__ cnt, float* __restrict__ invdeg){
  __shared__ unsigned tm[NCLS];
  int t = threadIdx.x;
  for (int i=t;i<NCLS;i+=256) tm[i] = decode_mask(i);
  __syncthreads();
  int id = blockIdx.x*256 + t;
  if (id >= 16*NCLS) return;
  int ci = id / NCLS, r = id % NCLS;
  unsigned m = tm[r];
  float deg = 0.f;
  const float* cc = cnt + ci*NCLS;
  for (int tp=0; tp<NCLS; ++tp)
    if (m & tm[tp]) deg += cc[tp];
  invdeg[id] = 1.0f / fmaxf(deg, 1.0f);
}

// ---------------- stage D3: per-class agg via inclusion-exclusion ----------------
__global__ __launch_bounds__(128) void k_as(const float* __restrict__ F,
    const float* __restrict__ UP, const float* __restrict__ invdeg, float* __restrict__ agg){
  int r = blockIdx.x, ci = blockIdx.y, t = threadIdx.x;
  int c = 2; while (c < 14 && C3i(c+1) <= r) c++;
  int rem = r - C3i(c);
  int b = 1; while (b < c-1 && C2i(b+1) <= rem) b++;
  int a = rem - C2i(b);
  const float* U = UP + ci*NUP*HH;
  int pab = 15 + C2i(b) + a;
  int pac = 15 + C2i(c) + a;
  int pbc = 15 + C2i(c) + b;
  float v = U[a*HH+t] + U[b*HH+t] + U[c*HH+t]
          - U[pab*HH+t] - U[pac*HH+t] - U[pbc*HH+t]
          + F[(ci*NCLS+r)*HH + t];
  agg[(ci*NCLS+r)*HH + t] = v * invdeg[ci*NCLS+r];
}

// ---------------- stage E: hc = relu(agg@Wl^T + bl + feat@Wr^T) per masked node ----------------
#define GRP 8
__global__ __launch_bounds__(128) void k_hc(const float* __restrict__ X,
    const float* __restrict__ Wl, const float* __restrict__ blv, const float* __restrict__ Wr,
    const int* __restrict__ ranks, const float* __restrict__ fiSel,
    const int* __restrict__ nodeCnt, const int* __restrict__ nodeList,
    const float* __restrict__ agg, float* __restrict__ hcBuf, float* __restrict__ sums){
  int ci = blockIdx.y;
  int cntc = nodeCnt[ci];
  int base = blockIdx.x * GRP;
  if (base >= cntc) return;
  __shared__ float aggs[GRP][HH];
  __shared__ float fts[GRP][HH];
  __shared__ int es[GRP];
  int t = threadIdx.x;
  if (t < GRP) es[t] = (base + t < cntc) ? nodeList[ci*NN + base + t] : -1;
  __syncthreads();
  for (int r=0;r<GRP;++r){
    int e = es[r];
    if (e >= 0){
      int rank = ranks[e];
      aggs[r][t] = agg[(ci*NCLS+rank)*HH + t];
      int n = e >> 2;
      fts[r][t] = X[(n*CCC+ci)*HH + t] * fiSel[e];
    } else { aggs[r][t] = 0.f; fts[r][t] = 0.f; }
  }
  __syncthreads();
  float acc[GRP];
  #pragma unroll
  for (int r=0;r<GRP;++r) acc[r]=0.f;
  const float* wl = Wl + (ci*HH + t)*HH;
  const float* wr = Wr + (ci*HH + t)*HH;
  for (int h=0; h<HH; h+=4){
    float4 a4 = *(const float4*)(wl + h);
    float4 b4 = *(const float4*)(wr + h);
    #pragma unroll
    for (int r=0;r<GRP;++r){
      acc[r] += aggs[r][h]*a4.x + aggs[r][h+1]*a4.y + aggs[r][h+2]*a4.z + aggs[r][h+3]*a4.w
              + fts[r][h]*b4.x + fts[r][h+1]*b4.y + fts[r][h+2]*b4.z + fts[r][h+3]*b4.w;
    }
  }
  float bl_ = blv[ci*HH + t];
  float s1=0.f, s2=0.f;
  #pragma unroll
  for (int r=0;r<GRP;++r){
    int e = es[r];
    if (e >= 0){
      float hc = acc[r] + bl_;
      hc = hc>0.f ? hc : 0.f;
      hcBuf[e*HH + t] = hc;
      s1 += hc; s2 += hc*hc;
    }
  }
  __syncthreads();
  float* red1 = &aggs[0][0];
  float* red2 = &fts[0][0];
  red1[t]=s1; red2[t]=s2;
  __syncthreads();
  for (int off=64; off>0; off>>=1){
    if (t < off){ red1[t]+=red1[t+off]; red2[t]+=red2[t+off]; }
    __syncthreads();
  }
  if (t==0){ atomicAdd(&sums[ci], red1[0]); atomicAdd(&sums[16+ci], red2[0]); }
}

// ---------------- stage F: masked mean/var normalize, write output ----------------
__global__ __launch_bounds__(256) void k_out(const float* __restrict__ hcBuf,
    const int* __restrict__ cols, const int* __restrict__ nodeCnt,
    const float* __restrict__ sums, float* __restrict__ out){
  int idx = blockIdx.x*256 + threadIdx.x;     // < 12288*128
  int e = idx >> 7;
  int ci = cols[e];
  float cntf = (float)nodeCnt[ci];
  float nel = fmaxf(cntf * (float)HH, 1.0f);
  float mu = sums[ci]/nel;
  float var = sums[16+ci]/nel - mu*mu;
  out[idx] = (hcBuf[idx]-mu)/sqrtf(var+EPSF);
}

extern "C" void kernel_launch(void* const* d_in, const int* in_sizes, int n_in,
                              void* d_out, int out_size, void* d_ws, size_t ws_size,
                              hipStream_t stream){
  const float* X    = (const float*)d_in[0];
  const float* W1   = (const float*)d_in[1];
  const float* b1   = (const float*)d_in[2];
  const float* ln_g = (const float*)d_in[3];
  const float* ln_b = (const float*)d_in[4];
  const float* W2   = (const float*)d_in[5];
  const float* b2   = (const float*)d_in[6];
  const float* Wl   = (const float*)d_in[7];
  const float* bl   = (const float*)d_in[8];
  const float* Wr   = (const float*)d_in[9];
  float* ws = (float*)d_ws;
  float* F      = ws + OFF_F;
  float* cnt    = ws + OFF_CNT;
  float* sums   = ws + OFF_SUMS;
  int*   nodeCnt= (int*)(ws + OFF_NCNT);
  float* logits = ws + OFF_LOGITS;
  int*   cols   = (int*)(ws + OFF_COLS);
  int*   ranks  = (int*)(ws + OFF_RANKS);
  float* fiSel  = ws + OFF_FISEL;
  int*   nodeList=(int*)(ws + OFF_NLIST);
  float* UP     = ws + OFF_UP;
  float* agg    = ws + OFF_AGG;
  float* invdeg = ws + OFF_INVDEG;
  float* hcBuf  = ws + OFF_HC;
  float* out    = (float*)d_out;

  hipMemsetAsync(ws, 0, (size_t)ZERO_FLOATS*sizeof(float), stream);

  k_logits<<<dim3(NN*CCC/ROWS), dim3(128), 0, stream>>>(X, W1, b1, ln_g, ln_b, W2, b2, logits);
  k_topk  <<<dim3((NN+255)/256), dim3(256), 0, stream>>>(logits, cols, ranks, fiSel, nodeCnt, nodeList);
  k_accF  <<<dim3(NN*KTOP), dim3(128), 0, stream>>>(X, cols, ranks, fiSel, F, cnt);
  k_up    <<<dim3(NUP,16), dim3(128), 0, stream>>>(F, UP);
  k_deg   <<<dim3((16*NCLS+255)/256), dim3(256), 0, stream>>>(cnt, invdeg);
  k_as    <<<dim3(NCLS,16), dim3(128), 0, stream>>>(F, UP, invdeg, agg);
  k_hc    <<<dim3(NN/GRP,16), dim3(128), 0, stream>>>(X, Wl, bl, Wr, ranks, fiSel, nodeCnt, nodeList, agg, hcBuf, sums);
  k_out   <<<dim3(NN*KTOP*HH/256), dim3(256), 0, stream>>>(hcBuf, cols, nodeCnt, sums, out);
}

// Round 2
// 291.773 us; speedup vs baseline: 1.2823x; 1.2823x over previous
//
#include <hip/hip_runtime.h>
#include <hip/hip_bf16.h>

#define NN 3072
#define CCC 16
#define HH 128
#define KTOP 4
#define NCLS 455   // C(15,3)
#define NUP 120    // 15 singles + 105 pairs
#define EPSF 1e-5f

// ---------------- ws layout (float offsets) ----------------
#define OFF_F       0
#define SZ_F        (16*NCLS*HH)            // 931840
#define OFF_CNT     (OFF_F + SZ_F)          // class counts (float), 7280
#define SZ_CNT      (16*NCLS)
#define OFF_SUMS    (OFF_CNT + SZ_CNT)      // sumHc[16], sumSq[16]
#define SZ_SUMS     32
#define OFF_NCNT    (OFF_SUMS + SZ_SUMS)    // int nodeCnt[16]
#define SZ_NCNT     16
#define ZERO_FLOATS (OFF_NCNT + SZ_NCNT)
#define OFF_LOGITS  ZERO_FLOATS
#define SZ_LOGITS   (NN*CCC)
#define OFF_COLS    (OFF_LOGITS + SZ_LOGITS)   // int, per (n,slot)
#define SZ_E        (NN*KTOP)
#define OFF_RANKS   (OFF_COLS + SZ_E)          // int
#define OFF_FISEL   (OFF_RANKS + SZ_E)         // float
#define OFF_NLIST   (OFF_FISEL + SZ_E)         // int, 16*NN
#define SZ_NLIST    (16*NN)
#define OFF_UP      (OFF_NLIST + SZ_NLIST)     // 16*120*128
#define SZ_UP       (16*NUP*HH)
#define OFF_AGG     (OFF_UP + SZ_UP)           // 16*455*128 (reused in-place for AggWl)
#define OFF_INVDEG  (OFF_AGG + SZ_F)           // unused now (kept for layout stability)
#define OFF_HC      (OFF_INVDEG + SZ_CNT)      // 12288*128
#define SZ_HC       (NN*KTOP*HH)

__device__ __forceinline__ int C2i(int x){ return x*(x-1)/2; }
__device__ __forceinline__ int C3i(int x){ return x*(x-1)*(x-2)/6; }

// rank -> triple bitmask over 15 relabeled columns
__device__ __forceinline__ unsigned decode_mask(int r){
  int c = 2; while (c < 14 && C3i(c+1) <= r) c++;
  int rem = r - C3i(c);
  int b = 1; while (b < c-1 && C2i(b+1) <= rem) b++;
  int a = rem - C2i(b);
  return (1u<<a) | (1u<<b) | (1u<<c);
}

// ================= stage A: z=relu(X@W1^T+b1); LN; logit=zn.W2+b2 =================
// 2D register-tiled GEMM: 64 rows x 128 cols per block, 256 threads,
// each thread 4 rows x 8 cols. Weights staged k-major in LDS.
#define MT 64
#define KC 32
__global__ __launch_bounds__(256) void k_logits(const float* __restrict__ X,
    const float* __restrict__ W1, const float* __restrict__ b1,
    const float* __restrict__ ln_g, const float* __restrict__ ln_b,
    const float* __restrict__ W2, const float* __restrict__ b2,
    float* __restrict__ logits){
  __shared__ float xs[MT][132];      // 64 rows x 128 k, pad 132 (16B-aligned rows, bank-spread)
  __shared__ float wch[KC][128];     // k-major weight chunk
  int t = threadIdx.x;
  int tr = t >> 4;                   // 0..15 row group
  int tc = t & 15;                   // 0..15 col group
  int base = blockIdx.x * MT;        // flat row = n*C + c (49152 rows / 64 = 768 blocks exact)

  // stage activations
  for (int idx = t; idx < MT*32; idx += 256){
    int r = idx >> 5, c4 = (idx & 31) << 2;
    float4 v = *(const float4*)(X + (size_t)(base + r)*HH + c4);
    xs[r][c4] = v.x; xs[r][c4+1] = v.y; xs[r][c4+2] = v.z; xs[r][c4+3] = v.w;
  }

  float acc[4][8];
  #pragma unroll
  for (int i=0;i<4;++i)
    #pragma unroll
    for (int j=0;j<8;++j) acc[i][j]=0.f;

  for (int k0 = 0; k0 < HH; k0 += KC){
    __syncthreads();
    // stage W chunk transposed to k-major
    {
      int o = t & 127, half = t >> 7;
      #pragma unroll
      for (int q = 0; q < 2; ++q){
        int kk = half*16 + q*8;
        float4 a = *(const float4*)(W1 + o*HH + k0 + kk);
        float4 b = *(const float4*)(W1 + o*HH + k0 + kk + 4);
        wch[kk+0][o]=a.x; wch[kk+1][o]=a.y; wch[kk+2][o]=a.z; wch[kk+3][o]=a.w;
        wch[kk+4][o]=b.x; wch[kk+5][o]=b.y; wch[kk+6][o]=b.z; wch[kk+7][o]=b.w;
      }
    }
    __syncthreads();
    const float* x0 = &xs[tr*4+0][k0];
    const float* x1 = &xs[tr*4+1][k0];
    const float* x2 = &xs[tr*4+2][k0];
    const float* x3 = &xs[tr*4+3][k0];
    #pragma unroll 8
    for (int k = 0; k < KC; ++k){
      float a0 = x0[k], a1 = x1[k], a2 = x2[k], a3 = x3[k];
      float4 wA = *(const float4*)&wch[k][tc*4];
      float4 wB = *(const float4*)&wch[k][64 + tc*4];
      float w[8] = {wA.x,wA.y,wA.z,wA.w,wB.x,wB.y,wB.z,wB.w};
      #pragma unroll
      for (int j=0;j<8;++j){
        acc[0][j] += a0*w[j]; acc[1][j] += a1*w[j];
        acc[2][j] += a2*w[j]; acc[3][j] += a3*w[j];
      }
    }
  }

  // epilogue: relu + LN + dot(W2)
  float4 bA = *(const float4*)(b1 + tc*4),  bB = *(const float4*)(b1 + 64 + tc*4);
  float4 gA = *(const float4*)(ln_g + tc*4), gB = *(const float4*)(ln_g + 64 + tc*4);
  float4 lA = *(const float4*)(ln_b + tc*4), lB = *(const float4*)(ln_b + 64 + tc*4);
  float4 wA2 = *(const float4*)(W2 + tc*4),  wB2 = *(const float4*)(W2 + 64 + tc*4);
  float bv[8] = {bA.x,bA.y,bA.z,bA.w,bB.x,bB.y,bB.z,bB.w};
  float gv[8] = {gA.x,gA.y,gA.z,gA.w,gB.x,gB.y,gB.z,gB.w};
  float lv[8] = {lA.x,lA.y,lA.z,lA.w,lB.x,lB.y,lB.z,lB.w};
  float wv[8] = {wA2.x,wA2.y,wA2.z,wA2.w,wB2.x,wB2.y,wB2.z,wB2.w};
  float b2v = b2[0];
  #pragma unroll
  for (int i=0;i<4;++i){
    float s1=0.f, s2=0.f;
    #pragma unroll
    for (int j=0;j<8;++j){
      float z = acc[i][j] + bv[j]; z = z>0.f?z:0.f;
      acc[i][j] = z; s1 += z; s2 += z*z;
    }
    #pragma unroll
    for (int m=1;m<16;m<<=1){ s1 += __shfl_xor(s1,m); s2 += __shfl_xor(s2,m); }
    float mu = s1/(float)HH;
    float var = s2/(float)HH - mu*mu;
    float rs = 1.0f/sqrtf(var+EPSF);
    float s3 = 0.f;
    #pragma unroll
    for (int j=0;j<8;++j){
      float zn = (acc[i][j]-mu)*rs*gv[j] + lv[j];
      s3 += zn*wv[j];
    }
    #pragma unroll
    for (int m=1;m<16;m<<=1) s3 += __shfl_xor(s3,m);
    if (tc == 0) logits[base + tr*4 + i] = s3 + b2v;
  }
}

// ================= stage B: softmax fi, top-4, class ranks, node lists =================
__global__ __launch_bounds__(256) void k_topk(const float* __restrict__ logits,
    int* __restrict__ cols, int* __restrict__ ranks, float* __restrict__ fiSel,
    int* __restrict__ nodeCnt, int* __restrict__ nodeList){
  int n = blockIdx.x*256 + threadIdx.x;
  if (n >= NN) return;
  float l[CCC];
  #pragma unroll
  for (int c=0;c<CCC;++c) l[c] = logits[n*CCC+c];
  unsigned mask = 0;
  #pragma unroll
  for (int k=0;k<KTOP;++k){
    float best = -3e38f; int bi = 0;
    #pragma unroll
    for (int c=0;c<CCC;++c){
      bool taken = (mask>>c)&1u;
      if (!taken && l[c] > best){ best = l[c]; bi = c; }
    }
    mask |= 1u<<bi;
  }
  float m = -3e38f;
  #pragma unroll
  for (int c=0;c<CCC;++c) m = l[c]>m ? l[c] : m;
  float s = 0.f;
  #pragma unroll
  for (int c=0;c<CCC;++c) s += expf(l[c]-m);
  float inv = 1.0f/s;
  unsigned m2 = mask;
  for (int j=0;j<KTOP;++j){
    int ci = __ffs(m2)-1; m2 &= m2-1u;
    unsigned rest = mask & ~(1u<<ci);
    int v[3]; unsigned r2 = rest;
    #pragma unroll
    for (int q=0;q<3;++q){ int col = __ffs(r2)-1; r2 &= r2-1u; v[q] = col - (col>ci ? 1:0); }
    int rank = C3i(v[2]) + C2i(v[1]) + v[0];
    int e4 = n*KTOP + j;
    cols[e4] = ci; ranks[e4] = rank;
    fiSel[e4] = expf(logits[n*CCC+ci]-m)*inv;
    int pos = atomicAdd(&nodeCnt[ci], 1);
    nodeList[ci*NN + pos] = e4;
  }
}

// ================= stage C: class feature sums =================
__global__ __launch_bounds__(256) void k_accF(const float* __restrict__ X,
    const int* __restrict__ cols, const int* __restrict__ ranks,
    const float* __restrict__ fiSel, float* __restrict__ F, float* __restrict__ cnt){
  int e = blockIdx.x*2 + (threadIdx.x>>7);
  int h = threadIdx.x & 127;
  int ci = cols[e], rank = ranks[e];
  float fi = fiSel[e];
  int n = e >> 2;
  float v = X[(n*CCC+ci)*HH + h] * fi;
  atomicAdd(&F[(ci*NCLS+rank)*HH + h], v);
  if (h==0) atomicAdd(&cnt[ci*NCLS+rank], 1.0f);
}

// ================= stage D1: singles U (15) and pairs P (105) per ci =================
__global__ __launch_bounds__(128) void k_up(const float* __restrict__ F, float* __restrict__ UP){
  __shared__ unsigned tm[NCLS];
  int t = threadIdx.x;
  for (int i=t;i<NCLS;i+=128) tm[i] = decode_mask(i);
  __syncthreads();
  int s = blockIdx.x, ci = blockIdx.y;
  unsigned need;
  if (s < 15) need = 1u<<s;
  else {
    int p = s-15;
    int pb = 1; while (pb < 14 && C2i(pb+1) <= p) pb++;
    int pa = p - C2i(pb);
    need = (1u<<pa)|(1u<<pb);
  }
  float acc = 0.f;
  const float* Fc = F + ci*NCLS*HH;
  for (int tp=0; tp<NCLS; ++tp)
    if ((tm[tp] & need) == need) acc += Fc[tp*HH + t];
  UP[(ci*NUP+s)*HH + t] = acc;
}

// ================= stage D2: per-class agg via inclusion-exclusion (+deg fused) =================
__global__ __launch_bounds__(128) void k_as(const float* __restrict__ F,
    const float* __restrict__ UP, const float* __restrict__ cnt, float* __restrict__ agg){
  __shared__ unsigned tm[NCLS];
  __shared__ float dred[2];
  int t = threadIdx.x;
  for (int i=t;i<NCLS;i+=128) tm[i] = decode_mask(i);
  __syncthreads();
  int r = blockIdx.x, ci = blockIdx.y;
  unsigned m = tm[r];
  float d = 0.f;
  const float* cc = cnt + ci*NCLS;
  for (int tp=t; tp<NCLS; tp+=128)
    if (m & tm[tp]) d += cc[tp];
  #pragma unroll
  for (int mm=1; mm<64; mm<<=1) d += __shfl_xor(d, mm);
  if ((t&63)==0) dred[t>>6] = d;
  __syncthreads();
  float invd = 1.0f / fmaxf(dred[0]+dred[1], 1.0f);
  int c = 2; while (c < 14 && C3i(c+1) <= r) c++;
  int rem = r - C3i(c);
  int b = 1; while (b < c-1 && C2i(b+1) <= rem) b++;
  int a = rem - C2i(b);
  const float* U = UP + ci*NUP*HH;
  int pab = 15 + C2i(b) + a;
  int pac = 15 + C2i(c) + a;
  int pbc = 15 + C2i(c) + b;
  float v = U[a*HH+t] + U[b*HH+t] + U[c*HH+t]
          - U[pab*HH+t] - U[pac*HH+t] - U[pbc*HH+t]
          + F[(ci*NCLS+r)*HH + t];
  agg[(ci*NCLS+r)*HH + t] = v * invd;
}

// ================= stage E1: AggWl = Agg @ Wl^T + bl (per class, in-place) =================
__global__ __launch_bounds__(256) void k_aggwl(float* __restrict__ agg,
    const float* __restrict__ Wl, const float* __restrict__ bl){
  __shared__ float xs[MT][132];
  __shared__ float wch[KC][128];
  int t = threadIdx.x;
  int tr = t >> 4, tc = t & 15;
  int ci = blockIdx.y;
  int base = blockIdx.x * MT;          // rows of the 455-class table

  float* A = agg + (size_t)ci*NCLS*HH;
  for (int idx = t; idx < MT*32; idx += 256){
    int r = idx >> 5, c4 = (idx & 31) << 2;
    int rg = base + r; if (rg > NCLS-1) rg = NCLS-1;
    float4 v = *(const float4*)(A + (size_t)rg*HH + c4);
    xs[r][c4] = v.x; xs[r][c4+1] = v.y; xs[r][c4+2] = v.z; xs[r][c4+3] = v.w;
  }

  float acc[4][8];
  #pragma unroll
  for (int i=0;i<4;++i)
    #pragma unroll
    for (int j=0;j<8;++j) acc[i][j]=0.f;

  const float* W = Wl + (size_t)ci*HH*HH;
  for (int k0 = 0; k0 < HH; k0 += KC){
    __syncthreads();
    {
      int o = t & 127, half = t >> 7;
      #pragma unroll
      for (int q = 0; q < 2; ++q){
        int kk = half*16 + q*8;
        float4 a = *(const float4*)(W + o*HH + k0 + kk);
        float4 b = *(const float4*)(W + o*HH + k0 + kk + 4);
        wch[kk+0][o]=a.x; wch[kk+1][o]=a.y; wch[kk+2][o]=a.z; wch[kk+3][o]=a.w;
        wch[kk+4][o]=b.x; wch[kk+5][o]=b.y; wch[kk+6][o]=b.z; wch[kk+7][o]=b.w;
      }
    }
    __syncthreads();
    const float* x0 = &xs[tr*4+0][k0];
    const float* x1 = &xs[tr*4+1][k0];
    const float* x2 = &xs[tr*4+2][k0];
    const float* x3 = &xs[tr*4+3][k0];
    #pragma unroll 8
    for (int k = 0; k < KC; ++k){
      float a0 = x0[k], a1 = x1[k], a2 = x2[k], a3 = x3[k];
      float4 wA = *(const float4*)&wch[k][tc*4];
      float4 wB = *(const float4*)&wch[k][64 + tc*4];
      float w[8] = {wA.x,wA.y,wA.z,wA.w,wB.x,wB.y,wB.z,wB.w};
      #pragma unroll
      for (int j=0;j<8;++j){
        acc[0][j] += a0*w[j]; acc[1][j] += a1*w[j];
        acc[2][j] += a2*w[j]; acc[3][j] += a3*w[j];
      }
    }
  }
  float4 blA = *(const float4*)(bl + ci*HH + tc*4);
  float4 blB = *(const float4*)(bl + ci*HH + 64 + tc*4);
  #pragma unroll
  for (int i=0;i<4;++i){
    int row = base + tr*4 + i;
    if (row < NCLS){
      float4 oA = { acc[i][0]+blA.x, acc[i][1]+blA.y, acc[i][2]+blA.z, acc[i][3]+blA.w };
      float4 oB = { acc[i][4]+blB.x, acc[i][5]+blB.y, acc[i][6]+blB.z, acc[i][7]+blB.w };
      *(float4*)(A + (size_t)row*HH + tc*4) = oA;
      *(float4*)(A + (size_t)row*HH + 64 + tc*4) = oB;
    }
  }
}

// ================= stage E2: hc = relu(AggWl[class] + fi*X @ Wr^T) per node =================
__global__ __launch_bounds__(256) void k_hc2(const float* __restrict__ X,
    const float* __restrict__ Wr,
    const int* __restrict__ ranks, const float* __restrict__ fiSel,
    const int* __restrict__ nodeCnt, const int* __restrict__ nodeList,
    const float* __restrict__ aggwl, float* __restrict__ hcBuf, float* __restrict__ sums){
  int ci = blockIdx.y;
  int cntc = nodeCnt[ci];
  int base = blockIdx.x * MT;
  if (base >= cntc) return;
  __shared__ float xs[MT][132];
  __shared__ float wch[KC][128];
  __shared__ int   es[MT];
  __shared__ float fis[MT];
  __shared__ int   rks[MT];
  __shared__ float rb[8];
  int t = threadIdx.x;
  int tr = t >> 4, tc = t & 15;
  if (t < MT){
    int p = base + t;
    if (p < cntc){
      int e = nodeList[ci*NN + p];
      es[t] = e; fis[t] = fiSel[e]; rks[t] = ranks[e];
    } else { es[t] = -1; fis[t] = 0.f; rks[t] = 0; }
  }
  __syncthreads();
  for (int idx = t; idx < MT*32; idx += 256){
    int r = idx >> 5, c4 = (idx & 31) << 2;
    int e = es[r];
    if (e >= 0){
      int n = e >> 2;
      float fi = fis[r];
      float4 v = *(const float4*)(X + (size_t)(n*CCC+ci)*HH + c4);
      xs[r][c4] = v.x*fi; xs[r][c4+1] = v.y*fi; xs[r][c4+2] = v.z*fi; xs[r][c4+3] = v.w*fi;
    } else {
      xs[r][c4]=0.f; xs[r][c4+1]=0.f; xs[r][c4+2]=0.f; xs[r][c4+3]=0.f;
    }
  }

  float acc[4][8];
  #pragma unroll
  for (int i=0;i<4;++i)
    #pragma unroll
    for (int j=0;j<8;++j) acc[i][j]=0.f;

  const float* W = Wr + (size_t)ci*HH*HH;
  for (int k0 = 0; k0 < HH; k0 += KC){
    __syncthreads();
    {
      int o = t & 127, half = t >> 7;
      #pragma unroll
      for (int q = 0; q < 2; ++q){
        int kk = half*16 + q*8;
        float4 a = *(const float4*)(W + o*HH + k0 + kk);
        float4 b = *(const float4*)(W + o*HH + k0 + kk + 4);
        wch[kk+0][o]=a.x; wch[kk+1][o]=a.y; wch[kk+2][o]=a.z; wch[kk+3][o]=a.w;
        wch[kk+4][o]=b.x; wch[kk+5][o]=b.y; wch[kk+6][o]=b.z; wch[kk+7][o]=b.w;
      }
    }
    __syncthreads();
    const float* x0 = &xs[tr*4+0][k0];
    const float* x1 = &xs[tr*4+1][k0];
    const float* x2 = &xs[tr*4+2][k0];
    const float* x3 = &xs[tr*4+3][k0];
    #pragma unroll 8
    for (int k = 0; k < KC; ++k){
      float a0 = x0[k], a1 = x1[k], a2 = x2[k], a3 = x3[k];
      float4 wA = *(const float4*)&wch[k][tc*4];
      float4 wB = *(const float4*)&wch[k][64 + tc*4];
      float w[8] = {wA.x,wA.y,wA.z,wA.w,wB.x,wB.y,wB.z,wB.w};
      #pragma unroll
      for (int j=0;j<8;++j){
        acc[0][j] += a0*w[j]; acc[1][j] += a1*w[j];
        acc[2][j] += a2*w[j]; acc[3][j] += a3*w[j];
      }
    }
  }

  float s1 = 0.f, s2 = 0.f;
  #pragma unroll
  for (int i=0;i<4;++i){
    int r = tr*4 + i;
    int e = es[r];
    if (e >= 0){
      int rank = rks[r];
      const float* G = aggwl + (size_t)(ci*NCLS + rank)*HH;
      float4 gA = *(const float4*)(G + tc*4);
      float4 gB = *(const float4*)(G + 64 + tc*4);
      float g[8] = {gA.x,gA.y,gA.z,gA.w,gB.x,gB.y,gB.z,gB.w};
      float hc[8];
      #pragma unroll
      for (int j=0;j<8;++j){
        float v = acc[i][j] + g[j];
        v = v>0.f ? v : 0.f;
        hc[j] = v; s1 += v; s2 += v*v;
      }
      float4 oA = {hc[0],hc[1],hc[2],hc[3]};
      float4 oB = {hc[4],hc[5],hc[6],hc[7]};
      *(float4*)(hcBuf + (size_t)e*HH + tc*4) = oA;
      *(float4*)(hcBuf + (size_t)e*HH + 64 + tc*4) = oB;
    }
  }
  #pragma unroll
  for (int m=1;m<64;m<<=1){ s1 += __shfl_xor(s1,m); s2 += __shfl_xor(s2,m); }
  int wid = t >> 6;
  if ((t&63)==0){ rb[wid] = s1; rb[4+wid] = s2; }
  __syncthreads();
  if (t==0){
    atomicAdd(&sums[ci],    rb[0]+rb[1]+rb[2]+rb[3]);
    atomicAdd(&sums[16+ci], rb[4]+rb[5]+rb[6]+rb[7]);
  }
}

// ================= stage F: masked mean/var normalize, write output =================
__global__ __launch_bounds__(256) void k_out(const float* __restrict__ hcBuf,
    const int* __restrict__ cols, const int* __restrict__ nodeCnt,
    const float* __restrict__ sums, float* __restrict__ out){
  int idx = blockIdx.x*256 + threadIdx.x;
  int e = idx >> 7;
  int ci = cols[e];
  float cntf = (float)nodeCnt[ci];
  float nel = fmaxf(cntf * (float)HH, 1.0f);
  float mu = sums[ci]/nel;
  float var = sums[16+ci]/nel - mu*mu;
  out[idx] = (hcBuf[idx]-mu)/sqrtf(var+EPSF);
}

extern "C" void kernel_launch(void* const* d_in, const int* in_sizes, int n_in,
                              void* d_out, int out_size, void* d_ws, size_t ws_size,
                              hipStream_t stream){
  const float* X    = (const float*)d_in[0];
  const float* W1   = (const float*)d_in[1];
  const float* b1   = (const float*)d_in[2];
  const float* ln_g = (const float*)d_in[3];
  const float* ln_b = (const float*)d_in[4];
  const float* W2   = (const float*)d_in[5];
  const float* b2   = (const float*)d_in[6];
  const float* Wl   = (const float*)d_in[7];
  const float* bl   = (const float*)d_in[8];
  const float* Wr   = (const float*)d_in[9];
  float* ws = (float*)d_ws;
  float* F      = ws + OFF_F;
  float* cnt    = ws + OFF_CNT;
  float* sums   = ws + OFF_SUMS;
  int*   nodeCnt= (int*)(ws + OFF_NCNT);
  float* logits = ws + OFF_LOGITS;
  int*   cols   = (int*)(ws + OFF_COLS);
  int*   ranks  = (int*)(ws + OFF_RANKS);
  float* fiSel  = ws + OFF_FISEL;
  int*   nodeList=(int*)(ws + OFF_NLIST);
  float* UP     = ws + OFF_UP;
  float* agg    = ws + OFF_AGG;
  float* hcBuf  = ws + OFF_HC;
  float* out    = (float*)d_out;

  hipMemsetAsync(ws, 0, (size_t)ZERO_FLOATS*sizeof(float), stream);

  k_logits<<<dim3(NN*CCC/MT), dim3(256), 0, stream>>>(X, W1, b1, ln_g, ln_b, W2, b2, logits);
  k_topk  <<<dim3((NN+255)/256), dim3(256), 0, stream>>>(logits, cols, ranks, fiSel, nodeCnt, nodeList);
  k_accF  <<<dim3(NN*KTOP/2), dim3(256), 0, stream>>>(X, cols, ranks, fiSel, F, cnt);
  k_up    <<<dim3(NUP,16), dim3(128), 0, stream>>>(F, UP);
  k_as    <<<dim3(NCLS,16), dim3(128), 0, stream>>>(F, UP, cnt, agg);
  k_aggwl <<<dim3((NCLS+MT-1)/MT,16), dim3(256), 0, stream>>>(agg, Wl, bl);
  k_hc2   <<<dim3((NN/MT),16), dim3(256), 0, stream>>>(X, Wr, ranks, fiSel, nodeCnt, nodeList, agg, hcBuf, sums);
  k_out   <<<dim3(NN*KTOP*HH/256), dim3(256), 0, stream>>>(hcBuf, cols, nodeCnt, sums, out);
}

// Round 3
// 253.621 us; speedup vs baseline: 1.4753x; 1.1504x over previous
//
#include <hip/hip_runtime.h>
#include <hip/hip_bf16.h>

#define NN 3072
#define CCC 16
#define HH 128
#define KTOP 4
#define NCLS 455   // C(15,3)
#define NUP 120    // 15 singles + 105 pairs
#define EPSF 1e-5f

// ---------------- ws layout (float offsets) ----------------
#define OFF_F       0
#define SZ_F        (16*NCLS*HH)            // 931840
#define OFF_CNT     (OFF_F + SZ_F)          // class counts (float), 7280
#define SZ_CNT      (16*NCLS)
#define OFF_SUMS    (OFF_CNT + SZ_CNT)      // sumHc[16], sumSq[16]
#define SZ_SUMS     32
#define OFF_NCNT    (OFF_SUMS + SZ_SUMS)    // int nodeCnt[16]
#define SZ_NCNT     16
#define ZERO_FLOATS (OFF_NCNT + SZ_NCNT)
#define OFF_LOGITS  ZERO_FLOATS
#define SZ_LOGITS   (NN*CCC)
#define OFF_COLS    (OFF_LOGITS + SZ_LOGITS)   // int, per (n,slot)
#define SZ_E        (NN*KTOP)
#define OFF_RANKS   (OFF_COLS + SZ_E)          // int
#define OFF_FISEL   (OFF_RANKS + SZ_E)         // float
#define OFF_NLIST   (OFF_FISEL + SZ_E)         // int, 16*NN
#define SZ_NLIST    (16*NN)
#define OFF_UP      (OFF_NLIST + SZ_NLIST)     // 16*120*128
#define SZ_UP       (16*NUP*HH)
#define OFF_AGG     (OFF_UP + SZ_UP)           // 16*455*128 (reused in-place for AggWl)
#define OFF_INVDEG  (OFF_AGG + SZ_F)           // unused now (kept for layout stability)
#define OFF_HC      (OFF_INVDEG + SZ_CNT)      // 12288*128
#define SZ_HC       (NN*KTOP*HH)

__device__ __forceinline__ int C2i(int x){ return x*(x-1)/2; }
__device__ __forceinline__ int C3i(int x){ return x*(x-1)*(x-2)/6; }

// rank -> triple bitmask over 15 relabeled columns
__device__ __forceinline__ unsigned decode_mask(int r){
  int c = 2; while (c < 14 && C3i(c+1) <= r) c++;
  int rem = r - C3i(c);
  int b = 1; while (b < c-1 && C2i(b+1) <= rem) b++;
  int a = rem - C2i(b);
  return (1u<<a) | (1u<<b) | (1u<<c);
}

// ================= stage A: z=relu(X@W1^T+b1); LN; logit=zn.W2+b2 =================
// 2D register-tiled GEMM: 64 rows x 128 cols per block, 256 threads,
// each thread 4 rows x 8 cols. Weights staged k-major in LDS.
#define MT 64
#define KC 32
__global__ __launch_bounds__(256) void k_logits(const float* __restrict__ X,
    const float* __restrict__ W1, const float* __restrict__ b1,
    const float* __restrict__ ln_g, const float* __restrict__ ln_b,
    const float* __restrict__ W2, const float* __restrict__ b2,
    float* __restrict__ logits){
  __shared__ float xs[MT][132];      // 64 rows x 128 k, pad 132 (16B-aligned rows, bank-spread)
  __shared__ float wch[KC][128];     // k-major weight chunk
  int t = threadIdx.x;
  int tr = t >> 4;                   // 0..15 row group
  int tc = t & 15;                   // 0..15 col group
  int base = blockIdx.x * MT;        // flat row = n*C + c (49152 rows / 64 = 768 blocks exact)

  // stage activations
  for (int idx = t; idx < MT*32; idx += 256){
    int r = idx >> 5, c4 = (idx & 31) << 2;
    float4 v = *(const float4*)(X + (size_t)(base + r)*HH + c4);
    xs[r][c4] = v.x; xs[r][c4+1] = v.y; xs[r][c4+2] = v.z; xs[r][c4+3] = v.w;
  }

  float acc[4][8];
  #pragma unroll
  for (int i=0;i<4;++i)
    #pragma unroll
    for (int j=0;j<8;++j) acc[i][j]=0.f;

  for (int k0 = 0; k0 < HH; k0 += KC){
    __syncthreads();
    // stage W chunk transposed to k-major
    {
      int o = t & 127, half = t >> 7;
      #pragma unroll
      for (int q = 0; q < 2; ++q){
        int kk = half*16 + q*8;
        float4 a = *(const float4*)(W1 + o*HH + k0 + kk);
        float4 b = *(const float4*)(W1 + o*HH + k0 + kk + 4);
        wch[kk+0][o]=a.x; wch[kk+1][o]=a.y; wch[kk+2][o]=a.z; wch[kk+3][o]=a.w;
        wch[kk+4][o]=b.x; wch[kk+5][o]=b.y; wch[kk+6][o]=b.z; wch[kk+7][o]=b.w;
      }
    }
    __syncthreads();
    const float* x0 = &xs[tr*4+0][k0];
    const float* x1 = &xs[tr*4+1][k0];
    const float* x2 = &xs[tr*4+2][k0];
    const float* x3 = &xs[tr*4+3][k0];
    #pragma unroll 8
    for (int k = 0; k < KC; ++k){
      float a0 = x0[k], a1 = x1[k], a2 = x2[k], a3 = x3[k];
      float4 wA = *(const float4*)&wch[k][tc*4];
      float4 wB = *(const float4*)&wch[k][64 + tc*4];
      float w[8] = {wA.x,wA.y,wA.z,wA.w,wB.x,wB.y,wB.z,wB.w};
      #pragma unroll
      for (int j=0;j<8;++j){
        acc[0][j] += a0*w[j]; acc[1][j] += a1*w[j];
        acc[2][j] += a2*w[j]; acc[3][j] += a3*w[j];
      }
    }
  }

  // epilogue: relu + LN + dot(W2)
  float4 bA = *(const float4*)(b1 + tc*4),  bB = *(const float4*)(b1 + 64 + tc*4);
  float4 gA = *(const float4*)(ln_g + tc*4), gB = *(const float4*)(ln_g + 64 + tc*4);
  float4 lA = *(const float4*)(ln_b + tc*4), lB = *(const float4*)(ln_b + 64 + tc*4);
  float4 wA2 = *(const float4*)(W2 + tc*4),  wB2 = *(const float4*)(W2 + 64 + tc*4);
  float bv[8] = {bA.x,bA.y,bA.z,bA.w,bB.x,bB.y,bB.z,bB.w};
  float gv[8] = {gA.x,gA.y,gA.z,gA.w,gB.x,gB.y,gB.z,gB.w};
  float lv[8] = {lA.x,lA.y,lA.z,lA.w,lB.x,lB.y,lB.z,lB.w};
  float wv[8] = {wA2.x,wA2.y,wA2.z,wA2.w,wB2.x,wB2.y,wB2.z,wB2.w};
  float b2v = b2[0];
  #pragma unroll
  for (int i=0;i<4;++i){
    float s1=0.f, s2=0.f;
    #pragma unroll
    for (int j=0;j<8;++j){
      float z = acc[i][j] + bv[j]; z = z>0.f?z:0.f;
      acc[i][j] = z; s1 += z; s2 += z*z;
    }
    #pragma unroll
    for (int m=1;m<16;m<<=1){ s1 += __shfl_xor(s1,m); s2 += __shfl_xor(s2,m); }
    float mu = s1/(float)HH;
    float var = s2/(float)HH - mu*mu;
    float rs = 1.0f/sqrtf(var+EPSF);
    float s3 = 0.f;
    #pragma unroll
    for (int j=0;j<8;++j){
      float zn = (acc[i][j]-mu)*rs*gv[j] + lv[j];
      s3 += zn*wv[j];
    }
    #pragma unroll
    for (int m=1;m<16;m<<=1) s3 += __shfl_xor(s3,m);
    if (tc == 0) logits[base + tr*4 + i] = s3 + b2v;
  }
}

// ================= stage B: softmax fi, top-4, class ranks, node lists =================
__global__ __launch_bounds__(256) void k_topk(const float* __restrict__ logits,
    int* __restrict__ cols, int* __restrict__ ranks, float* __restrict__ fiSel,
    int* __restrict__ nodeCnt, int* __restrict__ nodeList){
  int n = blockIdx.x*256 + threadIdx.x;
  if (n >= NN) return;
  float l[CCC];
  #pragma unroll
  for (int c=0;c<CCC;++c) l[c] = logits[n*CCC+c];
  unsigned mask = 0;
  #pragma unroll
  for (int k=0;k<KTOP;++k){
    float best = -3e38f; int bi = 0;
    #pragma unroll
    for (int c=0;c<CCC;++c){
      bool taken = (mask>>c)&1u;
      if (!taken && l[c] > best){ best = l[c]; bi = c; }
    }
    mask |= 1u<<bi;
  }
  float m = -3e38f;
  #pragma unroll
  for (int c=0;c<CCC;++c) m = l[c]>m ? l[c] : m;
  float s = 0.f;
  #pragma unroll
  for (int c=0;c<CCC;++c) s += expf(l[c]-m);
  float inv = 1.0f/s;
  unsigned m2 = mask;
  for (int j=0;j<KTOP;++j){
    int ci = __ffs(m2)-1; m2 &= m2-1u;
    unsigned rest = mask & ~(1u<<ci);
    int v[3]; unsigned r2 = rest;
    #pragma unroll
    for (int q=0;q<3;++q){ int col = __ffs(r2)-1; r2 &= r2-1u; v[q] = col - (col>ci ? 1:0); }
    int rank = C3i(v[2]) + C2i(v[1]) + v[0];
    int e4 = n*KTOP + j;
    cols[e4] = ci; ranks[e4] = rank;
    fiSel[e4] = expf(logits[n*CCC+ci]-m)*inv;
    int pos = atomicAdd(&nodeCnt[ci], 1);
    nodeList[ci*NN + pos] = e4;
  }
}

// ================= stage C: class feature sums =================
__global__ __launch_bounds__(256) void k_accF(const float* __restrict__ X,
    const int* __restrict__ cols, const int* __restrict__ ranks,
    const float* __restrict__ fiSel, float* __restrict__ F, float* __restrict__ cnt){
  int e = blockIdx.x*2 + (threadIdx.x>>7);
  int h = threadIdx.x & 127;
  int ci = cols[e], rank = ranks[e];
  float fi = fiSel[e];
  int n = e >> 2;
  float v = X[(n*CCC+ci)*HH + h] * fi;
  atomicAdd(&F[(ci*NCLS+rank)*HH + h], v);
  if (h==0) atomicAdd(&cnt[ci*NCLS+rank], 1.0f);
}

// ================= stage D1a: pairs P_xy = sum_z F[{x,y,z}] (13 direct summands) =================
__global__ __launch_bounds__(128) void k_pairs(const float* __restrict__ F, float* __restrict__ UP){
  int t = threadIdx.x;
  int p = blockIdx.x, ci = blockIdx.y;
  int pb = 1; while (pb < 14 && C2i(pb+1) <= p) pb++;
  int pa = p - C2i(pb);
  const float* Fc = F + (size_t)ci*NCLS*HH;
  float acc = 0.f;
  #pragma unroll
  for (int z = 0; z < 15; ++z){
    if (z == pa || z == pb) continue;
    int lo, mid, hi;
    if (z < pa){ lo = z;  mid = pa; hi = pb; }
    else if (z < pb){ lo = pa; mid = z;  hi = pb; }
    else { lo = pa; mid = pb; hi = z; }
    int rank = C3i(hi) + C2i(mid) + lo;
    acc += Fc[(size_t)rank*HH + t];
  }
  UP[((size_t)ci*NUP + 15 + p)*HH + t] = acc;
}

// ================= stage D1b: singles U_x = 0.5 * sum_{y!=x} P_xy =================
__global__ __launch_bounds__(128) void k_singles(float* __restrict__ UP){
  int t = threadIdx.x;
  int x = blockIdx.x, ci = blockIdx.y;
  const float* Pc = UP + ((size_t)ci*NUP + 15)*HH;
  float acc = 0.f;
  #pragma unroll
  for (int y = 0; y < 15; ++y){
    if (y == x) continue;
    int lo = x < y ? x : y, hi = x < y ? y : x;
    int pi = C2i(hi) + lo;
    acc += Pc[(size_t)pi*HH + t];
  }
  UP[((size_t)ci*NUP + x)*HH + t] = 0.5f*acc;
}

// ================= stage D2: per-class agg via inclusion-exclusion (+deg fused) =================
__global__ __launch_bounds__(128) void k_as(const float* __restrict__ F,
    const float* __restrict__ UP, const float* __restrict__ cnt, float* __restrict__ agg){
  __shared__ unsigned tm[NCLS];
  __shared__ float dred[2];
  int t = threadIdx.x;
  for (int i=t;i<NCLS;i+=128) tm[i] = decode_mask(i);
  __syncthreads();
  int r = blockIdx.x, ci = blockIdx.y;
  unsigned m = tm[r];
  float d = 0.f;
  const float* cc = cnt + ci*NCLS;
  for (int tp=t; tp<NCLS; tp+=128)
    if (m & tm[tp]) d += cc[tp];
  #pragma unroll
  for (int mm=1; mm<64; mm<<=1) d += __shfl_xor(d, mm);
  if ((t&63)==0) dred[t>>6] = d;
  __syncthreads();
  float invd = 1.0f / fmaxf(dred[0]+dred[1], 1.0f);
  int c = 2; while (c < 14 && C3i(c+1) <= r) c++;
  int rem = r - C3i(c);
  int b = 1; while (b < c-1 && C2i(b+1) <= rem) b++;
  int a = rem - C2i(b);
  const float* U = UP + ci*NUP*HH;
  int pab = 15 + C2i(b) + a;
  int pac = 15 + C2i(c) + a;
  int pbc = 15 + C2i(c) + b;
  float v = U[a*HH+t] + U[b*HH+t] + U[c*HH+t]
          - U[pab*HH+t] - U[pac*HH+t] - U[pbc*HH+t]
          + F[(ci*NCLS+r)*HH + t];
  agg[(ci*NCLS+r)*HH + t] = v * invd;
}

// ================= stage E1: AggWl = Agg @ Wl^T + bl (per class, in-place) =================
__global__ __launch_bounds__(256) void k_aggwl(float* __restrict__ agg,
    const float* __restrict__ Wl, const float* __restrict__ bl){
  __shared__ float xs[MT][132];
  __shared__ float wch[KC][128];
  int t = threadIdx.x;
  int tr = t >> 4, tc = t & 15;
  int ci = blockIdx.y;
  int base = blockIdx.x * MT;          // rows of the 455-class table

  float* A = agg + (size_t)ci*NCLS*HH;
  for (int idx = t; idx < MT*32; idx += 256){
    int r = idx >> 5, c4 = (idx & 31) << 2;
    int rg = base + r; if (rg > NCLS-1) rg = NCLS-1;
    float4 v = *(const float4*)(A + (size_t)rg*HH + c4);
    xs[r][c4] = v.x; xs[r][c4+1] = v.y; xs[r][c4+2] = v.z; xs[r][c4+3] = v.w;
  }

  float acc[4][8];
  #pragma unroll
  for (int i=0;i<4;++i)
    #pragma unroll
    for (int j=0;j<8;++j) acc[i][j]=0.f;

  const float* W = Wl + (size_t)ci*HH*HH;
  for (int k0 = 0; k0 < HH; k0 += KC){
    __syncthreads();
    {
      int o = t & 127, half = t >> 7;
      #pragma unroll
      for (int q = 0; q < 2; ++q){
        int kk = half*16 + q*8;
        float4 a = *(const float4*)(W + o*HH + k0 + kk);
        float4 b = *(const float4*)(W + o*HH + k0 + kk + 4);
        wch[kk+0][o]=a.x; wch[kk+1][o]=a.y; wch[kk+2][o]=a.z; wch[kk+3][o]=a.w;
        wch[kk+4][o]=b.x; wch[kk+5][o]=b.y; wch[kk+6][o]=b.z; wch[kk+7][o]=b.w;
      }
    }
    __syncthreads();
    const float* x0 = &xs[tr*4+0][k0];
    const float* x1 = &xs[tr*4+1][k0];
    const float* x2 = &xs[tr*4+2][k0];
    const float* x3 = &xs[tr*4+3][k0];
    #pragma unroll 8
    for (int k = 0; k < KC; ++k){
      float a0 = x0[k], a1 = x1[k], a2 = x2[k], a3 = x3[k];
      float4 wA = *(const float4*)&wch[k][tc*4];
      float4 wB = *(const float4*)&wch[k][64 + tc*4];
      float w[8] = {wA.x,wA.y,wA.z,wA.w,wB.x,wB.y,wB.z,wB.w};
      #pragma unroll
      for (int j=0;j<8;++j){
        acc[0][j] += a0*w[j]; acc[1][j] += a1*w[j];
        acc[2][j] += a2*w[j]; acc[3][j] += a3*w[j];
      }
    }
  }
  float4 blA = *(const float4*)(bl + ci*HH + tc*4);
  float4 blB = *(const float4*)(bl + ci*HH + 64 + tc*4);
  #pragma unroll
  for (int i=0;i<4;++i){
    int row = base + tr*4 + i;
    if (row < NCLS){
      float4 oA = { acc[i][0]+blA.x, acc[i][1]+blA.y, acc[i][2]+blA.z, acc[i][3]+blA.w };
      float4 oB = { acc[i][4]+blB.x, acc[i][5]+blB.y, acc[i][6]+blB.z, acc[i][7]+blB.w };
      *(float4*)(A + (size_t)row*HH + tc*4) = oA;
      *(float4*)(A + (size_t)row*HH + 64 + tc*4) = oB;
    }
  }
}

// ================= stage E2: hc = relu(AggWl[class] + fi*X @ Wr^T) per node =================
__global__ __launch_bounds__(256) void k_hc2(const float* __restrict__ X,
    const float* __restrict__ Wr,
    const int* __restrict__ ranks, const float* __restrict__ fiSel,
    const int* __restrict__ nodeCnt, const int* __restrict__ nodeList,
    const float* __restrict__ aggwl, float* __restrict__ hcBuf, float* __restrict__ sums){
  int ci = blockIdx.y;
  int cntc = nodeCnt[ci];
  int base = blockIdx.x * MT;
  if (base >= cntc) return;
  __shared__ float xs[MT][132];
  __shared__ float wch[KC][128];
  __shared__ int   es[MT];
  __shared__ float fis[MT];
  __shared__ int   rks[MT];
  __shared__ float rb[8];
  int t = threadIdx.x;
  int tr = t >> 4, tc = t & 15;
  if (t < MT){
    int p = base + t;
    if (p < cntc){
      int e = nodeList[ci*NN + p];
      es[t] = e; fis[t] = fiSel[e]; rks[t] = ranks[e];
    } else { es[t] = -1; fis[t] = 0.f; rks[t] = 0; }
  }
  __syncthreads();
  for (int idx = t; idx < MT*32; idx += 256){
    int r = idx >> 5, c4 = (idx & 31) << 2;
    int e = es[r];
    if (e >= 0){
      int n = e >> 2;
      float fi = fis[r];
      float4 v = *(const float4*)(X + (size_t)(n*CCC+ci)*HH + c4);
      xs[r][c4] = v.x*fi; xs[r][c4+1] = v.y*fi; xs[r][c4+2] = v.z*fi; xs[r][c4+3] = v.w*fi;
    } else {
      xs[r][c4]=0.f; xs[r][c4+1]=0.f; xs[r][c4+2]=0.f; xs[r][c4+3]=0.f;
    }
  }

  float acc[4][8];
  #pragma unroll
  for (int i=0;i<4;++i)
    #pragma unroll
    for (int j=0;j<8;++j) acc[i][j]=0.f;

  const float* W = Wr + (size_t)ci*HH*HH;
  for (int k0 = 0; k0 < HH; k0 += KC){
    __syncthreads();
    {
      int o = t & 127, half = t >> 7;
      #pragma unroll
      for (int q = 0; q < 2; ++q){
        int kk = half*16 + q*8;
        float4 a = *(const float4*)(W + o*HH + k0 + kk);
        float4 b = *(const float4*)(W + o*HH + k0 + kk + 4);
        wch[kk+0][o]=a.x; wch[kk+1][o]=a.y; wch[kk+2][o]=a.z; wch[kk+3][o]=a.w;
        wch[kk+4][o]=b.x; wch[kk+5][o]=b.y; wch[kk+6][o]=b.z; wch[kk+7][o]=b.w;
      }
    }
    __syncthreads();
    const float* x0 = &xs[tr*4+0][k0];
    const float* x1 = &xs[tr*4+1][k0];
    const float* x2 = &xs[tr*4+2][k0];
    const float* x3 = &xs[tr*4+3][k0];
    #pragma unroll 8
    for (int k = 0; k < KC; ++k){
      float a0 = x0[k], a1 = x1[k], a2 = x2[k], a3 = x3[k];
      float4 wA = *(const float4*)&wch[k][tc*4];
      float4 wB = *(const float4*)&wch[k][64 + tc*4];
      float w[8] = {wA.x,wA.y,wA.z,wA.w,wB.x,wB.y,wB.z,wB.w};
      #pragma unroll
      for (int j=0;j<8;++j){
        acc[0][j] += a0*w[j]; acc[1][j] += a1*w[j];
        acc[2][j] += a2*w[j]; acc[3][j] += a3*w[j];
      }
    }
  }

  float s1 = 0.f, s2 = 0.f;
  #pragma unroll
  for (int i=0;i<4;++i){
    int r = tr*4 + i;
    int e = es[r];
    if (e >= 0){
      int rank = rks[r];
      const float* G = aggwl + (size_t)(ci*NCLS + rank)*HH;
      float4 gA = *(const float4*)(G + tc*4);
      float4 gB = *(const float4*)(G + 64 + tc*4);
      float g[8] = {gA.x,gA.y,gA.z,gA.w,gB.x,gB.y,gB.z,gB.w};
      float hc[8];
      #pragma unroll
      for (int j=0;j<8;++j){
        float v = acc[i][j] + g[j];
        v = v>0.f ? v : 0.f;
        hc[j] = v; s1 += v; s2 += v*v;
      }
      float4 oA = {hc[0],hc[1],hc[2],hc[3]};
      float4 oB = {hc[4],hc[5],hc[6],hc[7]};
      *(float4*)(hcBuf + (size_t)e*HH + tc*4) = oA;
      *(float4*)(hcBuf + (size_t)e*HH + 64 + tc*4) = oB;
    }
  }
  #pragma unroll
  for (int m=1;m<64;m<<=1){ s1 += __shfl_xor(s1,m); s2 += __shfl_xor(s2,m); }
  int wid = t >> 6;
  if ((t&63)==0){ rb[wid] = s1; rb[4+wid] = s2; }
  __syncthreads();
  if (t==0){
    atomicAdd(&sums[ci],    rb[0]+rb[1]+rb[2]+rb[3]);
    atomicAdd(&sums[16+ci], rb[4]+rb[5]+rb[6]+rb[7]);
  }
}

// ================= stage F: masked mean/var normalize, write output =================
__global__ __launch_bounds__(256) void k_out(const float* __restrict__ hcBuf,
    const int* __restrict__ cols, const int* __restrict__ nodeCnt,
    const float* __restrict__ sums, float* __restrict__ out){
  int idx = blockIdx.x*256 + threadIdx.x;
  int e = idx >> 7;
  int ci = cols[e];
  float cntf = (float)nodeCnt[ci];
  float nel = fmaxf(cntf * (float)HH, 1.0f);
  float mu = sums[ci]/nel;
  float var = sums[16+ci]/nel - mu*mu;
  out[idx] = (hcBuf[idx]-mu)/sqrtf(var+EPSF);
}

extern "C" void kernel_launch(void* const* d_in, const int* in_sizes, int n_in,
                              void* d_out, int out_size, void* d_ws, size_t ws_size,
                              hipStream_t stream){
  const float* X    = (const float*)d_in[0];
  const float* W1   = (const float*)d_in[1];
  const float* b1   = (const float*)d_in[2];
  const float* ln_g = (const float*)d_in[3];
  const float* ln_b = (const float*)d_in[4];
  const float* W2   = (const float*)d_in[5];
  const float* b2   = (const float*)d_in[6];
  const float* Wl   = (const float*)d_in[7];
  const float* bl   = (const float*)d_in[8];
  const float* Wr   = (const float*)d_in[9];
  float* ws = (float*)d_ws;
  float* F      = ws + OFF_F;
  float* cnt    = ws + OFF_CNT;
  float* sums   = ws + OFF_SUMS;
  int*   nodeCnt= (int*)(ws + OFF_NCNT);
  float* logits = ws + OFF_LOGITS;
  int*   cols   = (int*)(ws + OFF_COLS);
  int*   ranks  = (int*)(ws + OFF_RANKS);
  float* fiSel  = ws + OFF_FISEL;
  int*   nodeList=(int*)(ws + OFF_NLIST);
  float* UP     = ws + OFF_UP;
  float* agg    = ws + OFF_AGG;
  float* hcBuf  = ws + OFF_HC;
  float* out    = (float*)d_out;

  hipMemsetAsync(ws, 0, (size_t)ZERO_FLOATS*sizeof(float), stream);

  k_logits<<<dim3(NN*CCC/MT), dim3(256), 0, stream>>>(X, W1, b1, ln_g, ln_b, W2, b2, logits);
  k_topk  <<<dim3((NN+255)/256), dim3(256), 0, stream>>>(logits, cols, ranks, fiSel, nodeCnt, nodeList);
  k_accF  <<<dim3(NN*KTOP/2), dim3(256), 0, stream>>>(X, cols, ranks, fiSel, F, cnt);
  k_pairs <<<dim3(105,16), dim3(128), 0, stream>>>(F, UP);
  k_singles<<<dim3(15,16), dim3(128), 0, stream>>>(UP);
  k_as    <<<dim3(NCLS,16), dim3(128), 0, stream>>>(F, UP, cnt, agg);
  k_aggwl <<<dim3((NCLS+MT-1)/MT,16), dim3(256), 0, stream>>>(agg, Wl, bl);
  k_hc2   <<<dim3((NN/MT),16), dim3(256), 0, stream>>>(X, Wr, ranks, fiSel, nodeCnt, nodeList, agg, hcBuf, sums);
  k_out   <<<dim3(NN*KTOP*HH/256), dim3(256), 0, stream>>>(hcBuf, cols, nodeCnt, sums, out);
}

// Round 4
// 206.847 us; speedup vs baseline: 1.8088x; 1.2261x over previous
//
#include <hip/hip_runtime.h>
#include <hip/hip_bf16.h>

#define NN 3072
#define CCC 16
#define HH 128
#define KTOP 4
#define NCLS 455   // C(15,3)
#define NUP 120    // 15 singles + 105 pairs
#define EPSF 1e-5f

// ---------------- ws layout (float offsets) ----------------
#define OFF_F       0
#define SZ_F        (16*NCLS*HH)            // 931840
#define OFF_CNT     (OFF_F + SZ_F)          // class counts (float), 7280
#define SZ_CNT      (16*NCLS)
#define OFF_SUMS    (OFF_CNT + SZ_CNT)      // sumHc[16], sumSq[16]
#define SZ_SUMS     32
#define OFF_NCNT    (OFF_SUMS + SZ_SUMS)    // int nodeCnt[16*16] (64B-padded per counter)
#define SZ_NCNT     256
#define ZERO_FLOATS (OFF_NCNT + SZ_NCNT)
#define OFF_LOGITS  ZERO_FLOATS
#define SZ_LOGITS   (NN*CCC)
#define OFF_COLS    (OFF_LOGITS + SZ_LOGITS)   // int, per (n,slot)
#define SZ_E        (NN*KTOP)
#define OFF_RANKS   (OFF_COLS + SZ_E)          // int
#define OFF_FISEL   (OFF_RANKS + SZ_E)         // float
#define OFF_NLIST   (OFF_FISEL + SZ_E)         // int, 16*NN
#define SZ_NLIST    (16*NN)
#define OFF_UP      (OFF_NLIST + SZ_NLIST)     // 16*120*128
#define SZ_UP       (16*NUP*HH)
#define OFF_AGG     (OFF_UP + SZ_UP)           // 16*455*128 (reused in-place for AggWl)
#define OFF_INVDEG  (OFF_AGG + SZ_F)           // unused now (kept for layout stability)
#define OFF_HC      (OFF_INVDEG + SZ_CNT)      // 12288*128
#define SZ_HC       (NN*KTOP*HH)

__device__ __forceinline__ int C2i(int x){ return x*(x-1)/2; }
__device__ __forceinline__ int C3i(int x){ return x*(x-1)*(x-2)/6; }

// rank -> triple bitmask over 15 relabeled columns
__device__ __forceinline__ unsigned decode_mask(int r){
  int c = 2; while (c < 14 && C3i(c+1) <= r) c++;
  int rem = r - C3i(c);
  int b = 1; while (b < c-1 && C2i(b+1) <= rem) b++;
  int a = rem - C2i(b);
  return (1u<<a) | (1u<<b) | (1u<<c);
}

// ================= stage A: z=relu(X@W1^T+b1); LN; logit=zn.W2+b2 =================
// 2D register-tiled GEMM: 64 rows x 128 cols per block, 256 threads,
// each thread 4 rows x 8 cols. Weights staged k-major in LDS.
#define MT 64
#define KC 32
__global__ __launch_bounds__(256) void k_logits(const float* __restrict__ X,
    const float* __restrict__ W1, const float* __restrict__ b1,
    const float* __restrict__ ln_g, const float* __restrict__ ln_b,
    const float* __restrict__ W2, const float* __restrict__ b2,
    float* __restrict__ logits){
  __shared__ float xs[MT][132];      // 64 rows x 128 k, pad 132 (16B-aligned rows, bank-spread)
  __shared__ float wch[KC][128];     // k-major weight chunk
  int t = threadIdx.x;
  int tr = t >> 4;                   // 0..15 row group
  int tc = t & 15;                   // 0..15 col group
  int base = blockIdx.x * MT;        // flat row = n*C + c (49152 rows / 64 = 768 blocks exact)

  // stage activations
  for (int idx = t; idx < MT*32; idx += 256){
    int r = idx >> 5, c4 = (idx & 31) << 2;
    float4 v = *(const float4*)(X + (size_t)(base + r)*HH + c4);
    xs[r][c4] = v.x; xs[r][c4+1] = v.y; xs[r][c4+2] = v.z; xs[r][c4+3] = v.w;
  }

  float acc[4][8];
  #pragma unroll
  for (int i=0;i<4;++i)
    #pragma unroll
    for (int j=0;j<8;++j) acc[i][j]=0.f;

  for (int k0 = 0; k0 < HH; k0 += KC){
    __syncthreads();
    // stage W chunk transposed to k-major
    {
      int o = t & 127, half = t >> 7;
      #pragma unroll
      for (int q = 0; q < 2; ++q){
        int kk = half*16 + q*8;
        float4 a = *(const float4*)(W1 + o*HH + k0 + kk);
        float4 b = *(const float4*)(W1 + o*HH + k0 + kk + 4);
        wch[kk+0][o]=a.x; wch[kk+1][o]=a.y; wch[kk+2][o]=a.z; wch[kk+3][o]=a.w;
        wch[kk+4][o]=b.x; wch[kk+5][o]=b.y; wch[kk+6][o]=b.z; wch[kk+7][o]=b.w;
      }
    }
    __syncthreads();
    const float* x0 = &xs[tr*4+0][k0];
    const float* x1 = &xs[tr*4+1][k0];
    const float* x2 = &xs[tr*4+2][k0];
    const float* x3 = &xs[tr*4+3][k0];
    #pragma unroll 8
    for (int k = 0; k < KC; ++k){
      float a0 = x0[k], a1 = x1[k], a2 = x2[k], a3 = x3[k];
      float4 wA = *(const float4*)&wch[k][tc*4];
      float4 wB = *(const float4*)&wch[k][64 + tc*4];
      float w[8] = {wA.x,wA.y,wA.z,wA.w,wB.x,wB.y,wB.z,wB.w};
      #pragma unroll
      for (int j=0;j<8;++j){
        acc[0][j] += a0*w[j]; acc[1][j] += a1*w[j];
        acc[2][j] += a2*w[j]; acc[3][j] += a3*w[j];
      }
    }
  }

  // epilogue: relu + LN + dot(W2)
  float4 bA = *(const float4*)(b1 + tc*4),  bB = *(const float4*)(b1 + 64 + tc*4);
  float4 gA = *(const float4*)(ln_g + tc*4), gB = *(const float4*)(ln_g + 64 + tc*4);
  float4 lA = *(const float4*)(ln_b + tc*4), lB = *(const float4*)(ln_b + 64 + tc*4);
  float4 wA2 = *(const float4*)(W2 + tc*4),  wB2 = *(const float4*)(W2 + 64 + tc*4);
  float bv[8] = {bA.x,bA.y,bA.z,bA.w,bB.x,bB.y,bB.z,bB.w};
  float gv[8] = {gA.x,gA.y,gA.z,gA.w,gB.x,gB.y,gB.z,gB.w};
  float lv[8] = {lA.x,lA.y,lA.z,lA.w,lB.x,lB.y,lB.z,lB.w};
  float wv[8] = {wA2.x,wA2.y,wA2.z,wA2.w,wB2.x,wB2.y,wB2.z,wB2.w};
  float b2v = b2[0];
  #pragma unroll
  for (int i=0;i<4;++i){
    float s1=0.f, s2=0.f;
    #pragma unroll
    for (int j=0;j<8;++j){
      float z = acc[i][j] + bv[j]; z = z>0.f?z:0.f;
      acc[i][j] = z; s1 += z; s2 += z*z;
    }
    #pragma unroll
    for (int m=1;m<16;m<<=1){ s1 += __shfl_xor(s1,m); s2 += __shfl_xor(s2,m); }
    float mu = s1/(float)HH;
    float var = s2/(float)HH - mu*mu;
    float rs = 1.0f/sqrtf(var+EPSF);
    float s3 = 0.f;
    #pragma unroll
    for (int j=0;j<8;++j){
      float zn = (acc[i][j]-mu)*rs*gv[j] + lv[j];
      s3 += zn*wv[j];
    }
    #pragma unroll
    for (int m=1;m<16;m<<=1) s3 += __shfl_xor(s3,m);
    if (tc == 0) logits[base + tr*4 + i] = s3 + b2v;
  }
}

// ================= stage B: softmax fi, top-4, class ranks, node lists =================
// Two-level aggregation: LDS per-block counters, then 16 global atomics per
// block to 64B-padded counters (was 12288 same-line fetch-adds = 50 us).
__global__ __launch_bounds__(256) void k_topk(const float* __restrict__ logits,
    int* __restrict__ cols, int* __restrict__ ranks, float* __restrict__ fiSel,
    int* __restrict__ nodeCnt, int* __restrict__ nodeList){
  __shared__ int lcnt[CCC];
  __shared__ int lbase[CCC];
  int t = threadIdx.x;
  if (t < CCC) lcnt[t] = 0;
  __syncthreads();
  int n = blockIdx.x*256 + t;
  float l[CCC];
  #pragma unroll
  for (int c=0;c<CCC;++c) l[c] = logits[n*CCC+c];
  unsigned mask = 0;
  #pragma unroll
  for (int k=0;k<KTOP;++k){
    float best = -3e38f; int bi = 0;
    #pragma unroll
    for (int c=0;c<CCC;++c){
      bool taken = (mask>>c)&1u;
      if (!taken && l[c] > best){ best = l[c]; bi = c; }
    }
    mask |= 1u<<bi;
  }
  float m = -3e38f;
  #pragma unroll
  for (int c=0;c<CCC;++c) m = l[c]>m ? l[c] : m;
  float s = 0.f;
  #pragma unroll
  for (int c=0;c<CCC;++c) s += expf(l[c]-m);
  float inv = 1.0f/s;
  int mycis[KTOP], mypos[KTOP];
  unsigned m2 = mask;
  for (int j=0;j<KTOP;++j){
    int ci = __ffs(m2)-1; m2 &= m2-1u;
    unsigned rest = mask & ~(1u<<ci);
    int v[3]; unsigned r2 = rest;
    #pragma unroll
    for (int q=0;q<3;++q){ int col = __ffs(r2)-1; r2 &= r2-1u; v[q] = col - (col>ci ? 1:0); }
    int rank = C3i(v[2]) + C2i(v[1]) + v[0];
    int e4 = n*KTOP + j;
    cols[e4] = ci; ranks[e4] = rank;
    fiSel[e4] = expf(l[ci]-m)*inv;
    mycis[j] = ci;
    mypos[j] = atomicAdd(&lcnt[ci], 1);
  }
  __syncthreads();
  if (t < CCC) lbase[t] = atomicAdd(&nodeCnt[t*16], lcnt[t]);
  __syncthreads();
  #pragma unroll
  for (int j=0;j<KTOP;++j){
    int ci = mycis[j];
    nodeList[ci*NN + lbase[ci] + mypos[j]] = n*KTOP + j;
  }
}

// ================= stage C: class feature sums =================
__global__ __launch_bounds__(256) void k_accF(const float* __restrict__ X,
    const int* __restrict__ cols, const int* __restrict__ ranks,
    const float* __restrict__ fiSel, float* __restrict__ F, float* __restrict__ cnt){
  int e = blockIdx.x*2 + (threadIdx.x>>7);
  int h = threadIdx.x & 127;
  int ci = cols[e], rank = ranks[e];
  float fi = fiSel[e];
  int n = e >> 2;
  float v = X[(n*CCC+ci)*HH + h] * fi;
  atomicAdd(&F[(ci*NCLS+rank)*HH + h], v);
  if (h==0) atomicAdd(&cnt[ci*NCLS+rank], 1.0f);
}

// ================= stage D1a: pairs P_xy = sum_z F[{x,y,z}] (13 direct summands) =================
__global__ __launch_bounds__(128) void k_pairs(const float* __restrict__ F, float* __restrict__ UP){
  int t = threadIdx.x;
  int p = blockIdx.x, ci = blockIdx.y;
  int pb = 1; while (pb < 14 && C2i(pb+1) <= p) pb++;
  int pa = p - C2i(pb);
  const float* Fc = F + (size_t)ci*NCLS*HH;
  float acc = 0.f;
  #pragma unroll
  for (int z = 0; z < 15; ++z){
    if (z == pa || z == pb) continue;
    int lo, mid, hi;
    if (z < pa){ lo = z;  mid = pa; hi = pb; }
    else if (z < pb){ lo = pa; mid = z;  hi = pb; }
    else { lo = pa; mid = pb; hi = z; }
    int rank = C3i(hi) + C2i(mid) + lo;
    acc += Fc[(size_t)rank*HH + t];
  }
  UP[((size_t)ci*NUP + 15 + p)*HH + t] = acc;
}

// ================= stage D1b: singles U_x = 0.5 * sum_{y!=x} P_xy =================
__global__ __launch_bounds__(128) void k_singles(float* __restrict__ UP){
  int t = threadIdx.x;
  int x = blockIdx.x, ci = blockIdx.y;
  const float* Pc = UP + ((size_t)ci*NUP + 15)*HH;
  float acc = 0.f;
  #pragma unroll
  for (int y = 0; y < 15; ++y){
    if (y == x) continue;
    int lo = x < y ? x : y, hi = x < y ? y : x;
    int pi = C2i(hi) + lo;
    acc += Pc[(size_t)pi*HH + t];
  }
  UP[((size_t)ci*NUP + x)*HH + t] = 0.5f*acc;
}

// ================= stage D2: per-class agg via inclusion-exclusion (+deg fused) =================
__global__ __launch_bounds__(128) void k_as(const float* __restrict__ F,
    const float* __restrict__ UP, const float* __restrict__ cnt, float* __restrict__ agg){
  __shared__ unsigned tm[NCLS];
  __shared__ float dred[2];
  int t = threadIdx.x;
  for (int i=t;i<NCLS;i+=128) tm[i] = decode_mask(i);
  __syncthreads();
  int r = blockIdx.x, ci = blockIdx.y;
  unsigned m = tm[r];
  float d = 0.f;
  const float* cc = cnt + ci*NCLS;
  for (int tp=t; tp<NCLS; tp+=128)
    if (m & tm[tp]) d += cc[tp];
  #pragma unroll
  for (int mm=1; mm<64; mm<<=1) d += __shfl_xor(d, mm);
  if ((t&63)==0) dred[t>>6] = d;
  __syncthreads();
  float invd = 1.0f / fmaxf(dred[0]+dred[1], 1.0f);
  int c = 2; while (c < 14 && C3i(c+1) <= r) c++;
  int rem = r - C3i(c);
  int b = 1; while (b < c-1 && C2i(b+1) <= rem) b++;
  int a = rem - C2i(b);
  const float* U = UP + ci*NUP*HH;
  int pab = 15 + C2i(b) + a;
  int pac = 15 + C2i(c) + a;
  int pbc = 15 + C2i(c) + b;
  float v = U[a*HH+t] + U[b*HH+t] + U[c*HH+t]
          - U[pab*HH+t] - U[pac*HH+t] - U[pbc*HH+t]
          + F[(ci*NCLS+r)*HH + t];
  agg[(ci*NCLS+r)*HH + t] = v * invd;
}

// ================= stage E1: AggWl = Agg @ Wl^T + bl (per class, in-place) =================
__global__ __launch_bounds__(256) void k_aggwl(float* __restrict__ agg,
    const float* __restrict__ Wl, const float* __restrict__ bl){
  __shared__ float xs[MT][132];
  __shared__ float wch[KC][128];
  int t = threadIdx.x;
  int tr = t >> 4, tc = t & 15;
  int ci = blockIdx.y;
  int base = blockIdx.x * MT;          // rows of the 455-class table

  float* A = agg + (size_t)ci*NCLS*HH;
  for (int idx = t; idx < MT*32; idx += 256){
    int r = idx >> 5, c4 = (idx & 31) << 2;
    int rg = base + r; if (rg > NCLS-1) rg = NCLS-1;
    float4 v = *(const float4*)(A + (size_t)rg*HH + c4);
    xs[r][c4] = v.x; xs[r][c4+1] = v.y; xs[r][c4+2] = v.z; xs[r][c4+3] = v.w;
  }

  float acc[4][8];
  #pragma unroll
  for (int i=0;i<4;++i)
    #pragma unroll
    for (int j=0;j<8;++j) acc[i][j]=0.f;

  const float* W = Wl + (size_t)ci*HH*HH;
  for (int k0 = 0; k0 < HH; k0 += KC){
    __syncthreads();
    {
      int o = t & 127, half = t >> 7;
      #pragma unroll
      for (int q = 0; q < 2; ++q){
        int kk = half*16 + q*8;
        float4 a = *(const float4*)(W + o*HH + k0 + kk);
        float4 b = *(const float4*)(W + o*HH + k0 + kk + 4);
        wch[kk+0][o]=a.x; wch[kk+1][o]=a.y; wch[kk+2][o]=a.z; wch[kk+3][o]=a.w;
        wch[kk+4][o]=b.x; wch[kk+5][o]=b.y; wch[kk+6][o]=b.z; wch[kk+7][o]=b.w;
      }
    }
    __syncthreads();
    const float* x0 = &xs[tr*4+0][k0];
    const float* x1 = &xs[tr*4+1][k0];
    const float* x2 = &xs[tr*4+2][k0];
    const float* x3 = &xs[tr*4+3][k0];
    #pragma unroll 8
    for (int k = 0; k < KC; ++k){
      float a0 = x0[k], a1 = x1[k], a2 = x2[k], a3 = x3[k];
      float4 wA = *(const float4*)&wch[k][tc*4];
      float4 wB = *(const float4*)&wch[k][64 + tc*4];
      float w[8] = {wA.x,wA.y,wA.z,wA.w,wB.x,wB.y,wB.z,wB.w};
      #pragma unroll
      for (int j=0;j<8;++j){
        acc[0][j] += a0*w[j]; acc[1][j] += a1*w[j];
        acc[2][j] += a2*w[j]; acc[3][j] += a3*w[j];
      }
    }
  }
  float4 blA = *(const float4*)(bl + ci*HH + tc*4);
  float4 blB = *(const float4*)(bl + ci*HH + 64 + tc*4);
  #pragma unroll
  for (int i=0;i<4;++i){
    int row = base + tr*4 + i;
    if (row < NCLS){
      float4 oA = { acc[i][0]+blA.x, acc[i][1]+blA.y, acc[i][2]+blA.z, acc[i][3]+blA.w };
      float4 oB = { acc[i][4]+blB.x, acc[i][5]+blB.y, acc[i][6]+blB.z, acc[i][7]+blB.w };
      *(float4*)(A + (size_t)row*HH + tc*4) = oA;
      *(float4*)(A + (size_t)row*HH + 64 + tc*4) = oB;
    }
  }
}

// ================= stage E2: hc = relu(AggWl[class] + fi*X @ Wr^T) per node =================
__global__ __launch_bounds__(256) void k_hc2(const float* __restrict__ X,
    const float* __restrict__ Wr,
    const int* __restrict__ ranks, const float* __restrict__ fiSel,
    const int* __restrict__ nodeCnt, const int* __restrict__ nodeList,
    const float* __restrict__ aggwl, float* __restrict__ hcBuf, float* __restrict__ sums){
  int ci = blockIdx.y;
  int cntc = nodeCnt[ci*16];
  int base = blockIdx.x * MT;
  if (base >= cntc) return;
  __shared__ float xs[MT][132];
  __shared__ float wch[KC][128];
  __shared__ int   es[MT];
  __shared__ float fis[MT];
  __shared__ int   rks[MT];
  __shared__ float rb[8];
  int t = threadIdx.x;
  int tr = t >> 4, tc = t & 15;
  if (t < MT){
    int p = base + t;
    if (p < cntc){
      int e = nodeList[ci*NN + p];
      es[t] = e; fis[t] = fiSel[e]; rks[t] = ranks[e];
    } else { es[t] = -1; fis[t] = 0.f; rks[t] = 0; }
  }
  __syncthreads();
  for (int idx = t; idx < MT*32; idx += 256){
    int r = idx >> 5, c4 = (idx & 31) << 2;
    int e = es[r];
    if (e >= 0){
      int n = e >> 2;
      float fi = fis[r];
      float4 v = *(const float4*)(X + (size_t)(n*CCC+ci)*HH + c4);
      xs[r][c4] = v.x*fi; xs[r][c4+1] = v.y*fi; xs[r][c4+2] = v.z*fi; xs[r][c4+3] = v.w*fi;
    } else {
      xs[r][c4]=0.f; xs[r][c4+1]=0.f; xs[r][c4+2]=0.f; xs[r][c4+3]=0.f;
    }
  }

  float acc[4][8];
  #pragma unroll
  for (int i=0;i<4;++i)
    #pragma unroll
    for (int j=0;j<8;++j) acc[i][j]=0.f;

  const float* W = Wr + (size_t)ci*HH*HH;
  for (int k0 = 0; k0 < HH; k0 += KC){
    __syncthreads();
    {
      int o = t & 127, half = t >> 7;
      #pragma unroll
      for (int q = 0; q < 2; ++q){
        int kk = half*16 + q*8;
        float4 a = *(const float4*)(W + o*HH + k0 + kk);
        float4 b = *(const float4*)(W + o*HH + k0 + kk + 4);
        wch[kk+0][o]=a.x; wch[kk+1][o]=a.y; wch[kk+2][o]=a.z; wch[kk+3][o]=a.w;
        wch[kk+4][o]=b.x; wch[kk+5][o]=b.y; wch[kk+6][o]=b.z; wch[kk+7][o]=b.w;
      }
    }
    __syncthreads();
    const float* x0 = &xs[tr*4+0][k0];
    const float* x1 = &xs[tr*4+1][k0];
    const float* x2 = &xs[tr*4+2][k0];
    const float* x3 = &xs[tr*4+3][k0];
    #pragma unroll 8
    for (int k = 0; k < KC; ++k){
      float a0 = x0[k], a1 = x1[k], a2 = x2[k], a3 = x3[k];
      float4 wA = *(const float4*)&wch[k][tc*4];
      float4 wB = *(const float4*)&wch[k][64 + tc*4];
      float w[8] = {wA.x,wA.y,wA.z,wA.w,wB.x,wB.y,wB.z,wB.w};
      #pragma unroll
      for (int j=0;j<8;++j){
        acc[0][j] += a0*w[j]; acc[1][j] += a1*w[j];
        acc[2][j] += a2*w[j]; acc[3][j] += a3*w[j];
      }
    }
  }

  float s1 = 0.f, s2 = 0.f;
  #pragma unroll
  for (int i=0;i<4;++i){
    int r = tr*4 + i;
    int e = es[r];
    if (e >= 0){
      int rank = rks[r];
      const float* G = aggwl + (size_t)(ci*NCLS + rank)*HH;
      float4 gA = *(const float4*)(G + tc*4);
      float4 gB = *(const float4*)(G + 64 + tc*4);
      float g[8] = {gA.x,gA.y,gA.z,gA.w,gB.x,gB.y,gB.z,gB.w};
      float hc[8];
      #pragma unroll
      for (int j=0;j<8;++j){
        float v = acc[i][j] + g[j];
        v = v>0.f ? v : 0.f;
        hc[j] = v; s1 += v; s2 += v*v;
      }
      float4 oA = {hc[0],hc[1],hc[2],hc[3]};
      float4 oB = {hc[4],hc[5],hc[6],hc[7]};
      *(float4*)(hcBuf + (size_t)e*HH + tc*4) = oA;
      *(float4*)(hcBuf + (size_t)e*HH + 64 + tc*4) = oB;
    }
  }
  #pragma unroll
  for (int m=1;m<64;m<<=1){ s1 += __shfl_xor(s1,m); s2 += __shfl_xor(s2,m); }
  int wid = t >> 6;
  if ((t&63)==0){ rb[wid] = s1; rb[4+wid] = s2; }
  __syncthreads();
  if (t==0){
    atomicAdd(&sums[ci],    rb[0]+rb[1]+rb[2]+rb[3]);
    atomicAdd(&sums[16+ci], rb[4]+rb[5]+rb[6]+rb[7]);
  }
}

// ================= stage F: masked mean/var normalize, write output =================
__global__ __launch_bounds__(256) void k_out(const float* __restrict__ hcBuf,
    const int* __restrict__ cols, const int* __restrict__ nodeCnt,
    const float* __restrict__ sums, float* __restrict__ out){
  int idx = blockIdx.x*256 + threadIdx.x;
  int e = idx >> 7;
  int ci = cols[e];
  float cntf = (float)nodeCnt[ci*16];
  float nel = fmaxf(cntf * (float)HH, 1.0f);
  float mu = sums[ci]/nel;
  float var = sums[16+ci]/nel - mu*mu;
  out[idx] = (hcBuf[idx]-mu)/sqrtf(var+EPSF);
}

extern "C" void kernel_launch(void* const* d_in, const int* in_sizes, int n_in,
                              void* d_out, int out_size, void* d_ws, size_t ws_size,
                              hipStream_t stream){
  const float* X    = (const float*)d_in[0];
  const float* W1   = (const float*)d_in[1];
  const float* b1   = (const float*)d_in[2];
  const float* ln_g = (const float*)d_in[3];
  const float* ln_b = (const float*)d_in[4];
  const float* W2   = (const float*)d_in[5];
  const float* b2   = (const float*)d_in[6];
  const float* Wl   = (const float*)d_in[7];
  const float* bl   = (const float*)d_in[8];
  const float* Wr   = (const float*)d_in[9];
  float* ws = (float*)d_ws;
  float* F      = ws + OFF_F;
  float* cnt    = ws + OFF_CNT;
  float* sums   = ws + OFF_SUMS;
  int*   nodeCnt= (int*)(ws + OFF_NCNT);
  float* logits = ws + OFF_LOGITS;
  int*   cols   = (int*)(ws + OFF_COLS);
  int*   ranks  = (int*)(ws + OFF_RANKS);
  float* fiSel  = ws + OFF_FISEL;
  int*   nodeList=(int*)(ws + OFF_NLIST);
  float* UP     = ws + OFF_UP;
  float* agg    = ws + OFF_AGG;
  float* hcBuf  = ws + OFF_HC;
  float* out    = (float*)d_out;

  hipMemsetAsync(ws, 0, (size_t)ZERO_FLOATS*sizeof(float), stream);

  k_logits<<<dim3(NN*CCC/MT), dim3(256), 0, stream>>>(X, W1, b1, ln_g, ln_b, W2, b2, logits);
  k_topk  <<<dim3(NN/256), dim3(256), 0, stream>>>(logits, cols, ranks, fiSel, nodeCnt, nodeList);
  k_accF  <<<dim3(NN*KTOP/2), dim3(256), 0, stream>>>(X, cols, ranks, fiSel, F, cnt);
  k_pairs <<<dim3(105,16), dim3(128), 0, stream>>>(F, UP);
  k_singles<<<dim3(15,16), dim3(128), 0, stream>>>(UP);
  k_as    <<<dim3(NCLS,16), dim3(128), 0, stream>>>(F, UP, cnt, agg);
  k_aggwl <<<dim3((NCLS+MT-1)/MT,16), dim3(256), 0, stream>>>(agg, Wl, bl);
  k_hc2   <<<dim3((NN/MT),16), dim3(256), 0, stream>>>(X, Wr, ranks, fiSel, nodeCnt, nodeList, agg, hcBuf, sums);
  k_out   <<<dim3(NN*KTOP*HH/256), dim3(256), 0, stream>>>(hcBuf, cols, nodeCnt, sums, out);
}